// Round 1
// baseline (94.746 us; speedup 1.0000x reference)
//
#include <hip/hip_runtime.h>
#include <math.h>

// Problem constants (x: (5,1,256,64,64) f32)
constexpr int NIMG = 5;
constexpr int CCH  = 256;   // channels (both c and d)
constexpr int HWP  = 4096;  // H*W
constexpr int PT   = CCH * HWP;  // pixels per image = 1048576

// -----------------------------------------------------------------------------
// Kernel 1: per-image channel-mixing GEMM producing
//   u[n,d,p] = x[n,d,p] - sum_c x[n,c,p]*(W1+W2)[c,d] - b[d]
//   v[n,d,p] = sum_c x[n,c,p]*W2[c,d]
// where W1 = w[0:256,:], W2 = w[256:512,:], w is (512,256) row-major.
// Tile: 64 d x 64 p per block, K-step 64, 256 threads, 4x4 micro-tile.
// -----------------------------------------------------------------------------
__global__ __launch_bounds__(256) void uv_gemm(
    const float* __restrict__ x, const float* __restrict__ w,
    const float* __restrict__ bias, float* __restrict__ u, float* __restrict__ v)
{
    const int t  = threadIdx.x;
    const int tp = t & 15;   // p-group 0..15
    const int td = t >> 4;   // d-group 0..15
    const int p0 = blockIdx.x * 64;
    const int d0 = blockIdx.y * 64;
    const int n  = blockIdx.z;
    const float* xn = x + (size_t)n * PT;

    __shared__ float xs [64][64];
    __shared__ float w2s[64][64];
    __shared__ float wss[64][64];

    float acc_s[4][4] = {};  // sum over c of x*(W1+W2)
    float acc_2[4][4] = {};  // sum over c of x*W2

    const int lr = t >> 4;        // stage row base 0..15
    const int lc = (t & 15) * 4;  // stage col 0..60

    for (int c0 = 0; c0 < CCH; c0 += 64) {
        #pragma unroll
        for (int k = 0; k < 4; ++k) {
            const int r = lr + k * 16;
            const float4 xv = *reinterpret_cast<const float4*>(
                &xn[(size_t)(c0 + r) * HWP + p0 + lc]);
            *reinterpret_cast<float4*>(&xs[r][lc]) = xv;
            const float4 w1v = *reinterpret_cast<const float4*>(
                &w[(size_t)(c0 + r) * CCH + d0 + lc]);
            const float4 w2v = *reinterpret_cast<const float4*>(
                &w[(size_t)(256 + c0 + r) * CCH + d0 + lc]);
            *reinterpret_cast<float4*>(&w2s[r][lc]) = w2v;
            const float4 wsv = {w1v.x + w2v.x, w1v.y + w2v.y,
                                w1v.z + w2v.z, w1v.w + w2v.w};
            *reinterpret_cast<float4*>(&wss[r][lc]) = wsv;
        }
        __syncthreads();

        #pragma unroll 8
        for (int cc = 0; cc < 64; ++cc) {
            const float4 xv  = *reinterpret_cast<const float4*>(&xs [cc][tp * 4]);
            const float4 wsv = *reinterpret_cast<const float4*>(&wss[cc][td * 4]);
            const float4 w2v = *reinterpret_cast<const float4*>(&w2s[cc][td * 4]);
            const float xa [4] = {xv.x, xv.y, xv.z, xv.w};
            const float wsa[4] = {wsv.x, wsv.y, wsv.z, wsv.w};
            const float w2a[4] = {w2v.x, w2v.y, w2v.z, w2v.w};
            #pragma unroll
            for (int i = 0; i < 4; ++i) {
                #pragma unroll
                for (int j = 0; j < 4; ++j) {
                    acc_s[i][j] = fmaf(wsa[i], xa[j], acc_s[i][j]);
                    acc_2[i][j] = fmaf(w2a[i], xa[j], acc_2[i][j]);
                }
            }
        }
        __syncthreads();
    }

    // Epilogue: u = x - acc_s - b[d], v = acc_2
    #pragma unroll
    for (int i = 0; i < 4; ++i) {
        const int d = d0 + td * 4 + i;
        const float bd = bias[d];
        const size_t base = (size_t)d * HWP + p0 + tp * 4;
        const float4 xv = *reinterpret_cast<const float4*>(&xn[base]);
        float4 uo, vo;
        uo.x = xv.x - acc_s[i][0] - bd;
        uo.y = xv.y - acc_s[i][1] - bd;
        uo.z = xv.z - acc_s[i][2] - bd;
        uo.w = xv.w - acc_s[i][3] - bd;
        vo.x = acc_2[i][0]; vo.y = acc_2[i][1];
        vo.z = acc_2[i][2]; vo.w = acc_2[i][3];
        *reinterpret_cast<float4*>(&u[(size_t)n * PT + base]) = uo;
        *reinterpret_cast<float4*>(&v[(size_t)n * PT + base]) = vo;
    }
}

// -----------------------------------------------------------------------------
// Kernel 2: per-pixel 5x5 edge matrix e[i][j] = |u[j]-v[i]|, row-norm over j,
// threshold e/max(norm,1e-12) > 0.35, out[i] = sum_j kept_e * x[j].
// float4-vectorized: each thread handles 4 consecutive pixels.
// -----------------------------------------------------------------------------
__global__ __launch_bounds__(256) void edge_out(
    const float* __restrict__ x, const float* __restrict__ u,
    const float* __restrict__ v, float* __restrict__ out)
{
    const size_t p = ((size_t)blockIdx.x * blockDim.x + threadIdx.x) * 4;
    if (p >= (size_t)PT) return;

    float xa[NIMG][4], ua[NIMG][4], va[NIMG][4];
    #pragma unroll
    for (int n2 = 0; n2 < NIMG; ++n2) {
        const float4 xv = *reinterpret_cast<const float4*>(&x[(size_t)n2 * PT + p]);
        const float4 uv = *reinterpret_cast<const float4*>(&u[(size_t)n2 * PT + p]);
        const float4 vv = *reinterpret_cast<const float4*>(&v[(size_t)n2 * PT + p]);
        xa[n2][0] = xv.x; xa[n2][1] = xv.y; xa[n2][2] = xv.z; xa[n2][3] = xv.w;
        ua[n2][0] = uv.x; ua[n2][1] = uv.y; ua[n2][2] = uv.z; ua[n2][3] = uv.w;
        va[n2][0] = vv.x; va[n2][1] = vv.y; va[n2][2] = vv.z; va[n2][3] = vv.w;
    }

    float oacc[NIMG][4];
    #pragma unroll
    for (int c = 0; c < 4; ++c) {
        #pragma unroll
        for (int i = 0; i < NIMG; ++i) {
            float e[NIMG];
            float sumsq = 0.0f;
            #pragma unroll
            for (int j = 0; j < NIMG; ++j) {
                e[j] = fabsf(ua[j][c] - va[i][c]);
                sumsq = fmaf(e[j], e[j], sumsq);
            }
            const float m = fmaxf(sqrtf(sumsq), 1e-12f);
            float h = 0.0f;
            #pragma unroll
            for (int j = 0; j < NIMG; ++j) {
                const float en = e[j] / m;
                if (en > 0.35f) h = fmaf(e[j], xa[j][c], h);
            }
            oacc[i][c] = h;
        }
    }

    #pragma unroll
    for (int i = 0; i < NIMG; ++i) {
        float4 ov = {oacc[i][0], oacc[i][1], oacc[i][2], oacc[i][3]};
        *reinterpret_cast<float4*>(&out[(size_t)i * PT + p]) = ov;
    }
}

extern "C" void kernel_launch(void* const* d_in, const int* in_sizes, int n_in,
                              void* d_out, int out_size, void* d_ws, size_t ws_size,
                              hipStream_t stream) {
    const float* x    = (const float*)d_in[0];
    const float* w    = (const float*)d_in[1];
    const float* bias = (const float*)d_in[2];
    float* out = (float*)d_out;

    float* u = (float*)d_ws;                       // 5 * 1Mi floats = 20 MB
    float* v = u + (size_t)NIMG * PT;              // another 20 MB

    dim3 g1(HWP / 64, CCH / 64, NIMG);             // 64 x 4 x 5 = 1280 blocks
    uv_gemm<<<g1, 256, 0, stream>>>(x, w, bias, u, v);

    const int n4 = PT / 4;                         // 262144 float4 pixels
    edge_out<<<(n4 + 255) / 256, 256, 0, stream>>>(x, u, v, out);
}